// Round 14
// baseline (6333.162 us; speedup 1.0000x reference)
//
#include <hip/hip_runtime.h>
#include <math.h>

#define NB    4
#define NPER  8192
#define MPER  4096
#define NTOT  32768
#define MTOT  16384
#define COUT  128

// d_out layout (floats): new_x [16384*128] | new_pos [16384*3] | new_batch [16384]
#define NEWPOS_OFF 2097152
#define NEWB_OFF   2146304

// workspace layout (bytes); ~17 MB
#define WS_H     0u           // 32768*128*4 = 16777216
#define WS_SQP   16777216u    // 32768*4
#define WS_SAMP  16908288u    // 16384*4
#define WS_PART  16973824u    // 64*128*4
#define WS_PART2 17006592u    // 64*128*4
#define WS_STAT  17039360u    // 256*4

// ---------------- sq_p + new_batch ----------------
// XLA:CPU fast-math emission of sum(p*p, -1): fma(z,z, fma(x,x, y*y)).
__global__ void misc_kernel(const float* __restrict__ pos, float* __restrict__ sqp,
                            float* __restrict__ out) {
  int g = blockIdx.x * 1024 + threadIdx.x;
  if (g < NTOT) {
    float x = pos[g * 3 + 0], y = pos[g * 3 + 1], z = pos[g * 3 + 2];
    sqp[g] = fmaf(z, z, fmaf(x, x, __fmul_rn(y, y)));
  }
  if (g < MTOT) out[NEWB_OFF + g] = (float)(g >> 12);
}

// ---------------- h_pre = x @ W  (+b) ----------------
__global__ __launch_bounds__(256) void matmul_kernel(const float* __restrict__ x,
                                                     const float* __restrict__ W,
                                                     const float* __restrict__ bias,
                                                     float* __restrict__ h) {
  __shared__ float xs[16][64];
  const int tid = threadIdx.x;
  const int rowbase = blockIdx.x * 16;
  for (int i = tid; i < 16 * 64; i += 256) xs[i >> 6][i & 63] = x[rowbase * 64 + i];
  __syncthreads();
  const int col = tid & 127;
  const int rs = (tid >> 7) * 8;
  float acc[8] = {0.f, 0.f, 0.f, 0.f, 0.f, 0.f, 0.f, 0.f};
  for (int k = 0; k < 64; ++k) {
    float wv = W[k * 128 + col];
#pragma unroll
    for (int r = 0; r < 8; ++r) acc[r] = fmaf(xs[rs + r][k], wv, acc[r]);
  }
  float bb = bias[col];
#pragma unroll
  for (int r = 0; r < 8; ++r) h[(rowbase + rs + r) * 128 + col] = acc[r] + bb;
}

// ---------------- BN partial sums (deterministic tree) ----------------
__global__ __launch_bounds__(256) void stats_kernel(const float* __restrict__ h,
                                                    float* __restrict__ part,
                                                    float* __restrict__ part2) {
  const int tid = threadIdx.x;
  const int col = tid & 127;
  const int half = tid >> 7;
  const int r0 = blockIdx.x * 512;
  float s = 0.f, s2 = 0.f;
  for (int r = r0 + half; r < r0 + 512; r += 2) {
    float v = h[r * 128 + col];
    s += v;
    s2 = fmaf(v, v, s2);
  }
  __shared__ float ps[2][128], ps2[2][128];
  ps[half][col] = s;
  ps2[half][col] = s2;
  __syncthreads();
  if (half == 0) {
    part[blockIdx.x * 128 + col] = ps[0][col] + ps[1][col];
    part2[blockIdx.x * 128 + col] = ps2[0][col] + ps2[1][col];
  }
}

__global__ void finalize_kernel(const float* __restrict__ part,
                                const float* __restrict__ part2,
                                float* __restrict__ stat) {
  int col = threadIdx.x;  // 128 threads
  float s = 0.f, s2 = 0.f;
  for (int i = 0; i < 64; ++i) {
    s += part[i * 128 + col];
    s2 += part2[i * 128 + col];
  }
  float mean = s / 32768.0f;
  float var = s2 / 32768.0f - mean * mean;
  float invstd = 1.0f / sqrtf(var + 1e-5f);
  stat[col] = mean;
  stat[128 + col] = invstd;
}

// ---------------- BN apply + exact GELU (in place on h) ----------------
__global__ __launch_bounds__(256) void bngelu_kernel(float* __restrict__ h,
                                                     const float* __restrict__ stat,
                                                     const float* __restrict__ gamma,
                                                     const float* __restrict__ beta) {
  int base = blockIdx.x * 2048 + threadIdx.x;
#pragma unroll
  for (int t = 0; t < 8; ++t) {
    int g = base + t * 256;
    int col = g & 127;
    float v = h[g];
    float z = (v - stat[col]) * stat[128 + col];
    z = z * gamma[col] + beta[col];
    float ge = 0.5f * z * (1.0f + erff(z * 0.70710678118654752440f));
    h[g] = ge;
  }
}

// ---------------- deterministic FPS, one block per cloud ----------------
// r13 dist math (frozen numerics) + latency-chain rebuild:
//  - wave reduce: 4 DPP row_shr levels (VALU, ~4cyc) + 2 shfl_xor levels,
//    carrying {key, x, y, z} payload -> lane 63 holds winner key AND xyz
//    (replaces 6 dependent ds_bpermute levels ~700 cyc + SELW owner chain)
//  - per-wave distinct slots, parity double-buffered -> ONE barrier/step,
//    zero atomics, zero lastpos round-trip (r6-validated ordering)
//  - consume: same-address broadcast LDS reads (free) + 7 register selects;
//    next-step lx/ly/lz stay in registers
#define FPS_DECL(i) float px##i, py##i, pz##i, dd##i;
#define FPS_LOAD(i)                    \
  {                                    \
    int n = tid + (i) * 512;           \
    px##i = p[n * 3 + 0];              \
    py##i = p[n * 3 + 1];              \
    pz##i = p[n * 3 + 2];              \
    dd##i = INFINITY;                  \
  }
#define FPS_PIN(i) \
  asm volatile("" : "+v"(px##i), "+v"(py##i), "+v"(pz##i));
#define FPS_DIST(i)                                                              \
  {                                                                              \
    float dx = __fsub_rn(px##i, lx), dy = __fsub_rn(py##i, ly),                  \
          dz = __fsub_rn(pz##i, lz);                                             \
    float d = fmaf(dz, dz, fmaf(dx, dx, __fmul_rn(dy, dy)));                     \
    float nd = fminf(dd##i, d);                                                  \
    dd##i = nd;                                                                  \
    unsigned long long key =                                                     \
        ((unsigned long long)__float_as_uint(nd) << 32) |                        \
        (unsigned int)(ntid - (i) * 512u);                                       \
    bool bt = key > bk;                                                          \
    bk = bt ? key : bk;                                                          \
    bx = bt ? px##i : bx;                                                        \
    by = bt ? py##i : by;                                                        \
    bz = bt ? pz##i : bz;                                                        \
  }
// one payload-reduce level via DPP (row_shr 1/2/4/8); invalid lanes keep own
#define FPS_DPP(CTRL)                                                            \
  {                                                                              \
    unsigned int a = (unsigned int)__builtin_amdgcn_update_dpp(                  \
        (int)klo, (int)klo, (CTRL), 0xf, 0xf, false);                            \
    unsigned int b2 = (unsigned int)__builtin_amdgcn_update_dpp(                 \
        (int)khi, (int)khi, (CTRL), 0xf, 0xf, false);                            \
    unsigned int c2 = (unsigned int)__builtin_amdgcn_update_dpp(                 \
        (int)xb, (int)xb, (CTRL), 0xf, 0xf, false);                              \
    unsigned int d2 = (unsigned int)__builtin_amdgcn_update_dpp(                 \
        (int)yb, (int)yb, (CTRL), 0xf, 0xf, false);                              \
    unsigned int e2 = (unsigned int)__builtin_amdgcn_update_dpp(                 \
        (int)zb, (int)zb, (CTRL), 0xf, 0xf, false);                              \
    unsigned long long nk = ((unsigned long long)b2 << 32) | a;                  \
    unsigned long long ok = ((unsigned long long)khi << 32) | klo;               \
    bool t = nk > ok;                                                            \
    klo = t ? a : klo; khi = t ? b2 : khi;                                       \
    xb = t ? c2 : xb; yb = t ? d2 : yb; zb = t ? e2 : zb;                        \
  }
#define FPS_SHF(OFF)                                                             \
  {                                                                              \
    unsigned int a = (unsigned int)__shfl_xor((int)klo, (OFF), 64);              \
    unsigned int b2 = (unsigned int)__shfl_xor((int)khi, (OFF), 64);             \
    unsigned int c2 = (unsigned int)__shfl_xor((int)xb, (OFF), 64);              \
    unsigned int d2 = (unsigned int)__shfl_xor((int)yb, (OFF), 64);              \
    unsigned int e2 = (unsigned int)__shfl_xor((int)zb, (OFF), 64);              \
    unsigned long long nk = ((unsigned long long)b2 << 32) | a;                  \
    unsigned long long ok = ((unsigned long long)khi << 32) | klo;               \
    bool t = nk > ok;                                                            \
    klo = t ? a : klo; khi = t ? b2 : khi;                                       \
    xb = t ? c2 : xb; yb = t ? d2 : yb; zb = t ? e2 : zb;                        \
  }
#define FPS_KSEL(ka, pa, kb, pb)                                                 \
  {                                                                              \
    bool t = (kb) > (ka);                                                        \
    ka = t ? (kb) : (ka);                                                        \
    pa.x = t ? pb.x : pa.x;                                                      \
    pa.y = t ? pb.y : pa.y;                                                      \
    pa.z = t ? pb.z : pa.z;                                                      \
  }

__global__ __launch_bounds__(512)
__attribute__((amdgpu_waves_per_eu(2, 2)))
void fps_kernel(const float* __restrict__ pos,
                int* __restrict__ samp,
                float* __restrict__ out) {
  const int b = blockIdx.x;
  const int tid = threadIdx.x;
  const int wv = tid >> 6;  // wave id 0..7
  const float* p = pos + b * NPER * 3;
  __shared__ __align__(16) unsigned long long ckey[2][8];
  __shared__ __align__(16) float4 cpos[2][8];
  FPS_DECL(0) FPS_DECL(1) FPS_DECL(2) FPS_DECL(3)
  FPS_DECL(4) FPS_DECL(5) FPS_DECL(6) FPS_DECL(7)
  FPS_DECL(8) FPS_DECL(9) FPS_DECL(10) FPS_DECL(11)
  FPS_DECL(12) FPS_DECL(13) FPS_DECL(14) FPS_DECL(15)
  FPS_LOAD(0) FPS_LOAD(1) FPS_LOAD(2) FPS_LOAD(3)
  FPS_LOAD(4) FPS_LOAD(5) FPS_LOAD(6) FPS_LOAD(7)
  FPS_LOAD(8) FPS_LOAD(9) FPS_LOAD(10) FPS_LOAD(11)
  FPS_LOAD(12) FPS_LOAD(13) FPS_LOAD(14) FPS_LOAD(15)
  FPS_PIN(0) FPS_PIN(1) FPS_PIN(2) FPS_PIN(3)
  FPS_PIN(4) FPS_PIN(5) FPS_PIN(6) FPS_PIN(7)
  FPS_PIN(8) FPS_PIN(9) FPS_PIN(10) FPS_PIN(11)
  FPS_PIN(12) FPS_PIN(13) FPS_PIN(14) FPS_PIN(15)
  const unsigned int ntid = ~(unsigned int)tid;
  // step 0 winner is point 0 (uniform reads -> scalar broadcast)
  float lx = p[0], ly = p[1], lz = p[2];
  if (tid == 0) {
    samp[b * MPER] = 0;
    out[NEWPOS_OFF + (b * MPER) * 3 + 0] = lx;
    out[NEWPOS_OFF + (b * MPER) * 3 + 1] = ly;
    out[NEWPOS_OFF + (b * MPER) * 3 + 2] = lz;
  }
  __syncthreads();
  for (int s = 1; s < MPER; ++s) {
    const int pr = s & 1;
    unsigned long long bk = 0ull;
    float bx = 0.f, by = 0.f, bz = 0.f;
    FPS_DIST(0) FPS_DIST(1) FPS_DIST(2) FPS_DIST(3)
    FPS_DIST(4) FPS_DIST(5) FPS_DIST(6) FPS_DIST(7)
    FPS_DIST(8) FPS_DIST(9) FPS_DIST(10) FPS_DIST(11)
    FPS_DIST(12) FPS_DIST(13) FPS_DIST(14) FPS_DIST(15)
    // wave-level payload reduce: rows via DPP, cross-row via shfl_xor
    unsigned int klo = (unsigned int)bk;
    unsigned int khi = (unsigned int)(bk >> 32);
    unsigned int xb = __float_as_uint(bx);
    unsigned int yb = __float_as_uint(by);
    unsigned int zb = __float_as_uint(bz);
    FPS_DPP(0x111)  // row_shr:1
    FPS_DPP(0x112)  // row_shr:2
    FPS_DPP(0x114)  // row_shr:4
    FPS_DPP(0x118)  // row_shr:8 -> lanes 15/31/47/63 hold row maxes
    FPS_SHF(16)
    FPS_SHF(32)     // lane 63 holds full wave max (+payload)
    if ((tid & 63) == 63) {
      ckey[pr][wv] = ((unsigned long long)khi << 32) | klo;
      cpos[pr][wv] = make_float4(__uint_as_float(xb), __uint_as_float(yb),
                                 __uint_as_float(zb), 0.f);
    }
    __syncthreads();
    // all threads reduce the 8 wave candidates (same-address broadcast reads)
    unsigned long long q0 = ckey[pr][0], q1 = ckey[pr][1];
    unsigned long long q2 = ckey[pr][2], q3 = ckey[pr][3];
    unsigned long long q4 = ckey[pr][4], q5 = ckey[pr][5];
    unsigned long long q6 = ckey[pr][6], q7 = ckey[pr][7];
    float4 P0 = cpos[pr][0], P1 = cpos[pr][1], P2 = cpos[pr][2], P3 = cpos[pr][3];
    float4 P4 = cpos[pr][4], P5 = cpos[pr][5], P6 = cpos[pr][6], P7 = cpos[pr][7];
    FPS_KSEL(q0, P0, q1, P1)
    FPS_KSEL(q2, P2, q3, P3)
    FPS_KSEL(q4, P4, q5, P5)
    FPS_KSEL(q6, P6, q7, P7)
    FPS_KSEL(q0, P0, q2, P2)
    FPS_KSEL(q4, P4, q6, P6)
    FPS_KSEL(q0, P0, q4, P4)
    const int widx = (int)(~(unsigned int)q0);
    lx = P0.x; ly = P0.y; lz = P0.z;
    if (tid == 0) {
      samp[b * MPER + s] = widx;
      out[NEWPOS_OFF + (b * MPER + s) * 3 + 0] = lx;
      out[NEWPOS_OFF + (b * MPER + s) * 3 + 1] = ly;
      out[NEWPOS_OFF + (b * MPER + s) * 3 + 2] = lz;
    }
    // no second barrier: parity double-buffer; step s+1 writes the other
    // slot set, and step s+2's overwrites are ordered by barrier s+1.
  }
}

// ---------------- kNN: Eigen-style ascending fma dot, expand-formula d2 ----------------
__global__ __launch_bounds__(256) void knn_kernel(const float* __restrict__ pos,
                                                  const float* __restrict__ sqp,
                                                  const int* __restrict__ samp,
                                                  const float* __restrict__ h,
                                                  float* __restrict__ out) {
  const int q = blockIdx.x;
  const int b = q >> 12;
  const int tid = threadIdx.x;
  const int gbase = b * NPER;
  __shared__ float dist[NPER];  // 32 KB
  __shared__ unsigned long long slot[2];
  __shared__ int nbr[16];
  const int sidx = samp[q];
  const float qx = pos[(gbase + sidx) * 3 + 0];
  const float qy = pos[(gbase + sidx) * 3 + 1];
  const float qz = pos[(gbase + sidx) * 3 + 2];
  const float sqq = sqp[gbase + sidx];
  if (tid == 0) {
    slot[0] = ~0ull;
    slot[1] = ~0ull;
  }
  unsigned long long lkey = ~0ull;
  for (int i = 0; i < 32; ++i) {
    int n = tid + i * 256;
    int g = gbase + n;
    // Eigen gebp: fma(q2,p2, fma(q1,p1, rn(q0*p0)))
    float dot = fmaf(qz, pos[g * 3 + 2],
                     fmaf(qy, pos[g * 3 + 1], __fmul_rn(qx, pos[g * 3 + 0])));
    // (sq_q + sq_p) - 2*dot, each op rounded
    float d2 = __fsub_rn(__fadd_rn(sqq, sqp[g]), __fmul_rn(2.0f, dot));
    dist[n] = d2;
    unsigned int ub = __float_as_uint(d2);
    ub = (ub & 0x80000000u) ? ~ub : (ub | 0x80000000u);  // monotone float->uint
    unsigned long long key = ((unsigned long long)ub << 32) | (unsigned int)n;
    lkey = (key < lkey) ? key : lkey;
  }
  __syncthreads();
  for (int r = 0; r < 16; ++r) {
    unsigned long long wk = lkey;
#pragma unroll
    for (int off = 1; off < 64; off <<= 1) {
      unsigned long long o = __shfl_xor(wk, off, 64);
      wk = (o < wk) ? o : wk;
    }
    if ((tid & 63) == 0) atomicMin(&slot[r & 1], wk);
    __syncthreads();
    unsigned long long w = slot[r & 1];
    int n = (int)(unsigned int)(w & 0xFFFFFFFFull);
    if (tid == 0) {
      nbr[r] = n;
      slot[(r & 1) ^ 1] = ~0ull;
    }
    if (tid == (n & 255)) {  // owner removes it and refreshes its local min
      dist[n] = INFINITY;
      lkey = ~0ull;
      for (int i = 0; i < 32; ++i) {
        int nn = tid + i * 256;
        unsigned int ub = __float_as_uint(dist[nn]);
        ub = (ub & 0x80000000u) ? ~ub : (ub | 0x80000000u);
        unsigned long long kk = ((unsigned long long)ub << 32) | (unsigned int)nn;
        lkey = (kk < lkey) ? kk : lkey;
      }
    }
    __syncthreads();
  }
  if (tid < COUT) {
    float mx = -INFINITY;
#pragma unroll
    for (int r = 0; r < 16; ++r) mx = fmaxf(mx, h[(gbase + nbr[r]) * 128 + tid]);
    out[q * 128 + tid] = mx;
  }
}

extern "C" void kernel_launch(void* const* d_in, const int* in_sizes, int n_in,
                              void* d_out, int out_size, void* d_ws, size_t ws_size,
                              hipStream_t stream) {
  (void)in_sizes; (void)n_in; (void)out_size; (void)ws_size;
  const float* x     = (const float*)d_in[0];
  const float* pos   = (const float*)d_in[1];
  const float* W     = (const float*)d_in[3];
  const float* bias  = (const float*)d_in[4];
  const float* gamma = (const float*)d_in[5];
  const float* beta  = (const float*)d_in[6];
  float* out = (float*)d_out;
  char* ws = (char*)d_ws;
  float* h     = (float*)(ws + WS_H);
  float* sqp   = (float*)(ws + WS_SQP);
  int*   samp  = (int*)(ws + WS_SAMP);
  float* part  = (float*)(ws + WS_PART);
  float* part2 = (float*)(ws + WS_PART2);
  float* stat  = (float*)(ws + WS_STAT);

  misc_kernel<<<dim3(32), dim3(1024), 0, stream>>>(pos, sqp, out);
  matmul_kernel<<<dim3(2048), dim3(256), 0, stream>>>(x, W, bias, h);
  stats_kernel<<<dim3(64), dim3(256), 0, stream>>>(h, part, part2);
  finalize_kernel<<<dim3(1), dim3(128), 0, stream>>>(part, part2, stat);
  bngelu_kernel<<<dim3(2048), dim3(256), 0, stream>>>(h, stat, gamma, beta);
  fps_kernel<<<dim3(NB), dim3(512), 0, stream>>>(pos, samp, out);
  knn_kernel<<<dim3(MTOT), dim3(256), 0, stream>>>(pos, sqp, samp, h, out);
}

// Round 15
// 5960.515 us; speedup vs baseline: 1.0625x; 1.0625x over previous
//
#include <hip/hip_runtime.h>
#include <math.h>

#define NB    4
#define NPER  8192
#define MPER  4096
#define NTOT  32768
#define MTOT  16384
#define COUT  128

// d_out layout (floats): new_x [16384*128] | new_pos [16384*3] | new_batch [16384]
#define NEWPOS_OFF 2097152
#define NEWB_OFF   2146304

// workspace layout (bytes); ~17 MB
#define WS_H     0u           // 32768*128*4 = 16777216
#define WS_SQP   16777216u    // 32768*4
#define WS_SAMP  16908288u    // 16384*4
#define WS_PART  16973824u    // 64*128*4
#define WS_PART2 17006592u    // 64*128*4
#define WS_STAT  17039360u    // 256*4

// ---------------- sq_p + new_batch ----------------
// XLA:CPU fast-math emission of sum(p*p, -1): fma(z,z, fma(x,x, y*y)).
__global__ void misc_kernel(const float* __restrict__ pos, float* __restrict__ sqp,
                            float* __restrict__ out) {
  int g = blockIdx.x * 1024 + threadIdx.x;
  if (g < NTOT) {
    float x = pos[g * 3 + 0], y = pos[g * 3 + 1], z = pos[g * 3 + 2];
    sqp[g] = fmaf(z, z, fmaf(x, x, __fmul_rn(y, y)));
  }
  if (g < MTOT) out[NEWB_OFF + g] = (float)(g >> 12);
}

// ---------------- h_pre = x @ W  (+b) ----------------
__global__ __launch_bounds__(256) void matmul_kernel(const float* __restrict__ x,
                                                     const float* __restrict__ W,
                                                     const float* __restrict__ bias,
                                                     float* __restrict__ h) {
  __shared__ float xs[16][64];
  const int tid = threadIdx.x;
  const int rowbase = blockIdx.x * 16;
  for (int i = tid; i < 16 * 64; i += 256) xs[i >> 6][i & 63] = x[rowbase * 64 + i];
  __syncthreads();
  const int col = tid & 127;
  const int rs = (tid >> 7) * 8;
  float acc[8] = {0.f, 0.f, 0.f, 0.f, 0.f, 0.f, 0.f, 0.f};
  for (int k = 0; k < 64; ++k) {
    float wv = W[k * 128 + col];
#pragma unroll
    for (int r = 0; r < 8; ++r) acc[r] = fmaf(xs[rs + r][k], wv, acc[r]);
  }
  float bb = bias[col];
#pragma unroll
  for (int r = 0; r < 8; ++r) h[(rowbase + rs + r) * 128 + col] = acc[r] + bb;
}

// ---------------- BN partial sums (deterministic tree) ----------------
__global__ __launch_bounds__(256) void stats_kernel(const float* __restrict__ h,
                                                    float* __restrict__ part,
                                                    float* __restrict__ part2) {
  const int tid = threadIdx.x;
  const int col = tid & 127;
  const int half = tid >> 7;
  const int r0 = blockIdx.x * 512;
  float s = 0.f, s2 = 0.f;
  for (int r = r0 + half; r < r0 + 512; r += 2) {
    float v = h[r * 128 + col];
    s += v;
    s2 = fmaf(v, v, s2);
  }
  __shared__ float ps[2][128], ps2[2][128];
  ps[half][col] = s;
  ps2[half][col] = s2;
  __syncthreads();
  if (half == 0) {
    part[blockIdx.x * 128 + col] = ps[0][col] + ps[1][col];
    part2[blockIdx.x * 128 + col] = ps2[0][col] + ps2[1][col];
  }
}

__global__ void finalize_kernel(const float* __restrict__ part,
                                const float* __restrict__ part2,
                                float* __restrict__ stat) {
  int col = threadIdx.x;  // 128 threads
  float s = 0.f, s2 = 0.f;
  for (int i = 0; i < 64; ++i) {
    s += part[i * 128 + col];
    s2 += part2[i * 128 + col];
  }
  float mean = s / 32768.0f;
  float var = s2 / 32768.0f - mean * mean;
  float invstd = 1.0f / sqrtf(var + 1e-5f);
  stat[col] = mean;
  stat[128 + col] = invstd;
}

// ---------------- BN apply + exact GELU (in place on h) ----------------
__global__ __launch_bounds__(256) void bngelu_kernel(float* __restrict__ h,
                                                     const float* __restrict__ stat,
                                                     const float* __restrict__ gamma,
                                                     const float* __restrict__ beta) {
  int base = blockIdx.x * 2048 + threadIdx.x;
#pragma unroll
  for (int t = 0; t < 8; ++t) {
    int g = base + t * 256;
    int col = g & 127;
    float v = h[g];
    float z = (v - stat[col]) * stat[128 + col];
    z = z * gamma[col] + beta[col];
    float ge = 0.5f * z * (1.0f + erff(z * 0.70710678118654752440f));
    h[g] = ge;
  }
}

// ---------------- deterministic FPS, one block per cloud ----------------
// Positions live in LDS (96 KB), not registers: r5-r14 proved the RA spills
// any register point-cache (invariant ~2.5x VALU inflation from scratch).
// LDS stride-1 reads are conflict-free (2 lanes/bank = free), ds pipe
// overlaps VALU across 4 waves/SIMD. Winner xyz = same-address broadcast
// LDS read -> no lastpos, no owner-select, ONE barrier/step via 3-phase
// slot rotation (clear@s after barrier_s happens-before atomics@s+2).
// Numerics and tie-break semantics bit-identical to the r5-verified kernel.
#define FPS_DD_DECL(i) float dd##i;
#define FPS_DIST(i)                                                              \
  {                                                                              \
    const int n = tid + (i) * 1024;                                              \
    float dx = __fsub_rn(lpx[n], lx), dy = __fsub_rn(lpy[n], ly),                \
          dz = __fsub_rn(lpz[n], lz);                                            \
    float d = fmaf(dz, dz, fmaf(dx, dx, __fmul_rn(dy, dy)));                     \
    float nd = fminf(dd##i, d);                                                  \
    dd##i = nd;                                                                  \
    unsigned long long key =                                                     \
        ((unsigned long long)__float_as_uint(nd) << 32) |                        \
        (unsigned int)(ntid - (i) * 1024u);                                      \
    bk = (key > bk) ? key : bk;                                                  \
  }

__global__ __launch_bounds__(1024)
__attribute__((amdgpu_waves_per_eu(4, 4)))
void fps_kernel(const float* __restrict__ pos,
                int* __restrict__ samp,
                float* __restrict__ out) {
  const int b = blockIdx.x;
  const int tid = threadIdx.x;
  const float* p = pos + b * NPER * 3;
  __shared__ float lpx[NPER];           // 32 KB
  __shared__ float lpy[NPER];           // 32 KB
  __shared__ float lpz[NPER];           // 32 KB
  __shared__ unsigned long long slot[3];
  for (int i = tid; i < NPER; i += 1024) {
    lpx[i] = p[i * 3 + 0];
    lpy[i] = p[i * 3 + 1];
    lpz[i] = p[i * 3 + 2];
  }
  FPS_DD_DECL(0) FPS_DD_DECL(1) FPS_DD_DECL(2) FPS_DD_DECL(3)
  FPS_DD_DECL(4) FPS_DD_DECL(5) FPS_DD_DECL(6) FPS_DD_DECL(7)
  dd0 = dd1 = dd2 = dd3 = dd4 = dd5 = dd6 = dd7 = INFINITY;
  const unsigned int ntid = ~(unsigned int)tid;
  if (tid == 0) {
    slot[0] = 0ull;
    slot[1] = 0ull;
    slot[2] = 0ull;
    samp[b * MPER] = 0;
    out[NEWPOS_OFF + (b * MPER) * 3 + 0] = p[0];
    out[NEWPOS_OFF + (b * MPER) * 3 + 1] = p[1];
    out[NEWPOS_OFF + (b * MPER) * 3 + 2] = p[2];
  }
  float lx = p[0], ly = p[1], lz = p[2];
  __syncthreads();
  for (int s = 1; s < MPER; ++s) {
    int pr = s % 3;
    int cl = pr + 2; if (cl >= 3) cl -= 3;  // (s+2)%3
    unsigned long long bk = 0ull;
    FPS_DIST(0) FPS_DIST(1) FPS_DIST(2) FPS_DIST(3)
    FPS_DIST(4) FPS_DIST(5) FPS_DIST(6) FPS_DIST(7)
#pragma unroll
    for (int off = 1; off < 64; off <<= 1) {
      unsigned long long o = __shfl_xor(bk, off, 64);
      bk = (o > bk) ? o : bk;
    }
    if ((tid & 63) == 0) atomicMax(&slot[pr], bk);
    __syncthreads();
    const unsigned long long w = slot[pr];
    const int widx = (int)(~(unsigned int)(w & 0xFFFFFFFFull));
    if (tid == 0) slot[cl] = 0ull;
    // winner xyz: same-address broadcast LDS reads (free)
    lx = lpx[widx];
    ly = lpy[widx];
    lz = lpz[widx];
    if (tid == 0) {
      samp[b * MPER + s] = widx;
      out[NEWPOS_OFF + (b * MPER + s) * 3 + 0] = lx;
      out[NEWPOS_OFF + (b * MPER + s) * 3 + 1] = ly;
      out[NEWPOS_OFF + (b * MPER + s) * 3 + 2] = lz;
    }
    // single barrier per step: 3-phase slots make clear/atomic/read ordered
    // (atomics into slot[pr] at step s+3 occur after barrier_{s+1} > clear@s)
  }
}

// ---------------- kNN: Eigen-style ascending fma dot, expand-formula d2 ----------------
__global__ __launch_bounds__(256) void knn_kernel(const float* __restrict__ pos,
                                                  const float* __restrict__ sqp,
                                                  const int* __restrict__ samp,
                                                  const float* __restrict__ h,
                                                  float* __restrict__ out) {
  const int q = blockIdx.x;
  const int b = q >> 12;
  const int tid = threadIdx.x;
  const int gbase = b * NPER;
  __shared__ float dist[NPER];  // 32 KB
  __shared__ unsigned long long slot[2];
  __shared__ int nbr[16];
  const int sidx = samp[q];
  const float qx = pos[(gbase + sidx) * 3 + 0];
  const float qy = pos[(gbase + sidx) * 3 + 1];
  const float qz = pos[(gbase + sidx) * 3 + 2];
  const float sqq = sqp[gbase + sidx];
  if (tid == 0) {
    slot[0] = ~0ull;
    slot[1] = ~0ull;
  }
  unsigned long long lkey = ~0ull;
  for (int i = 0; i < 32; ++i) {
    int n = tid + i * 256;
    int g = gbase + n;
    // Eigen gebp: fma(q2,p2, fma(q1,p1, rn(q0*p0)))
    float dot = fmaf(qz, pos[g * 3 + 2],
                     fmaf(qy, pos[g * 3 + 1], __fmul_rn(qx, pos[g * 3 + 0])));
    // (sq_q + sq_p) - 2*dot, each op rounded
    float d2 = __fsub_rn(__fadd_rn(sqq, sqp[g]), __fmul_rn(2.0f, dot));
    dist[n] = d2;
    unsigned int ub = __float_as_uint(d2);
    ub = (ub & 0x80000000u) ? ~ub : (ub | 0x80000000u);  // monotone float->uint
    unsigned long long key = ((unsigned long long)ub << 32) | (unsigned int)n;
    lkey = (key < lkey) ? key : lkey;
  }
  __syncthreads();
  for (int r = 0; r < 16; ++r) {
    unsigned long long wk = lkey;
#pragma unroll
    for (int off = 1; off < 64; off <<= 1) {
      unsigned long long o = __shfl_xor(wk, off, 64);
      wk = (o < wk) ? o : wk;
    }
    if ((tid & 63) == 0) atomicMin(&slot[r & 1], wk);
    __syncthreads();
    unsigned long long w = slot[r & 1];
    int n = (int)(unsigned int)(w & 0xFFFFFFFFull);
    if (tid == 0) {
      nbr[r] = n;
      slot[(r & 1) ^ 1] = ~0ull;
    }
    if (tid == (n & 255)) {  // owner removes it and refreshes its local min
      dist[n] = INFINITY;
      lkey = ~0ull;
      for (int i = 0; i < 32; ++i) {
        int nn = tid + i * 256;
        unsigned int ub = __float_as_uint(dist[nn]);
        ub = (ub & 0x80000000u) ? ~ub : (ub | 0x80000000u);
        unsigned long long kk = ((unsigned long long)ub << 32) | (unsigned int)nn;
        lkey = (kk < lkey) ? kk : lkey;
      }
    }
    __syncthreads();
  }
  if (tid < COUT) {
    float mx = -INFINITY;
#pragma unroll
    for (int r = 0; r < 16; ++r) mx = fmaxf(mx, h[(gbase + nbr[r]) * 128 + tid]);
    out[q * 128 + tid] = mx;
  }
}

extern "C" void kernel_launch(void* const* d_in, const int* in_sizes, int n_in,
                              void* d_out, int out_size, void* d_ws, size_t ws_size,
                              hipStream_t stream) {
  (void)in_sizes; (void)n_in; (void)out_size; (void)ws_size;
  const float* x     = (const float*)d_in[0];
  const float* pos   = (const float*)d_in[1];
  const float* W     = (const float*)d_in[3];
  const float* bias  = (const float*)d_in[4];
  const float* gamma = (const float*)d_in[5];
  const float* beta  = (const float*)d_in[6];
  float* out = (float*)d_out;
  char* ws = (char*)d_ws;
  float* h     = (float*)(ws + WS_H);
  float* sqp   = (float*)(ws + WS_SQP);
  int*   samp  = (int*)(ws + WS_SAMP);
  float* part  = (float*)(ws + WS_PART);
  float* part2 = (float*)(ws + WS_PART2);
  float* stat  = (float*)(ws + WS_STAT);

  misc_kernel<<<dim3(32), dim3(1024), 0, stream>>>(pos, sqp, out);
  matmul_kernel<<<dim3(2048), dim3(256), 0, stream>>>(x, W, bias, h);
  stats_kernel<<<dim3(64), dim3(256), 0, stream>>>(h, part, part2);
  finalize_kernel<<<dim3(1), dim3(128), 0, stream>>>(part, part2, stat);
  bngelu_kernel<<<dim3(2048), dim3(256), 0, stream>>>(h, stat, gamma, beta);
  fps_kernel<<<dim3(NB), dim3(1024), 0, stream>>>(pos, samp, out);
  knn_kernel<<<dim3(MTOT), dim3(256), 0, stream>>>(pos, sqp, samp, h, out);
}

// Round 16
// 4878.195 us; speedup vs baseline: 1.2983x; 1.2219x over previous
//
#include <hip/hip_runtime.h>
#include <math.h>

#define NB    4
#define NPER  8192
#define MPER  4096
#define NTOT  32768
#define MTOT  16384
#define COUT  128

// d_out layout (floats): new_x [16384*128] | new_pos [16384*3] | new_batch [16384]
#define NEWPOS_OFF 2097152
#define NEWB_OFF   2146304

// workspace layout (bytes); ~17 MB
#define WS_H     0u           // 32768*128*4 = 16777216
#define WS_SQP   16777216u    // 32768*4
#define WS_SAMP  16908288u    // 16384*4
#define WS_PART  16973824u    // 64*128*4
#define WS_PART2 17006592u    // 64*128*4
#define WS_STAT  17039360u    // 256*4

// ---------------- sq_p + new_batch ----------------
// XLA:CPU fast-math emission of sum(p*p, -1): fma(z,z, fma(x,x, y*y)).
__global__ void misc_kernel(const float* __restrict__ pos, float* __restrict__ sqp,
                            float* __restrict__ out) {
  int g = blockIdx.x * 1024 + threadIdx.x;
  if (g < NTOT) {
    float x = pos[g * 3 + 0], y = pos[g * 3 + 1], z = pos[g * 3 + 2];
    sqp[g] = fmaf(z, z, fmaf(x, x, __fmul_rn(y, y)));
  }
  if (g < MTOT) out[NEWB_OFF + g] = (float)(g >> 12);
}

// ---------------- h_pre = x @ W  (+b) ----------------
__global__ __launch_bounds__(256) void matmul_kernel(const float* __restrict__ x,
                                                     const float* __restrict__ W,
                                                     const float* __restrict__ bias,
                                                     float* __restrict__ h) {
  __shared__ float xs[16][64];
  const int tid = threadIdx.x;
  const int rowbase = blockIdx.x * 16;
  for (int i = tid; i < 16 * 64; i += 256) xs[i >> 6][i & 63] = x[rowbase * 64 + i];
  __syncthreads();
  const int col = tid & 127;
  const int rs = (tid >> 7) * 8;
  float acc[8] = {0.f, 0.f, 0.f, 0.f, 0.f, 0.f, 0.f, 0.f};
  for (int k = 0; k < 64; ++k) {
    float wv = W[k * 128 + col];
#pragma unroll
    for (int r = 0; r < 8; ++r) acc[r] = fmaf(xs[rs + r][k], wv, acc[r]);
  }
  float bb = bias[col];
#pragma unroll
  for (int r = 0; r < 8; ++r) h[(rowbase + rs + r) * 128 + col] = acc[r] + bb;
}

// ---------------- BN partial sums (deterministic tree) ----------------
__global__ __launch_bounds__(256) void stats_kernel(const float* __restrict__ h,
                                                    float* __restrict__ part,
                                                    float* __restrict__ part2) {
  const int tid = threadIdx.x;
  const int col = tid & 127;
  const int half = tid >> 7;
  const int r0 = blockIdx.x * 512;
  float s = 0.f, s2 = 0.f;
  for (int r = r0 + half; r < r0 + 512; r += 2) {
    float v = h[r * 128 + col];
    s += v;
    s2 = fmaf(v, v, s2);
  }
  __shared__ float ps[2][128], ps2[2][128];
  ps[half][col] = s;
  ps2[half][col] = s2;
  __syncthreads();
  if (half == 0) {
    part[blockIdx.x * 128 + col] = ps[0][col] + ps[1][col];
    part2[blockIdx.x * 128 + col] = ps2[0][col] + ps2[1][col];
  }
}

__global__ void finalize_kernel(const float* __restrict__ part,
                                const float* __restrict__ part2,
                                float* __restrict__ stat) {
  int col = threadIdx.x;  // 128 threads
  float s = 0.f, s2 = 0.f;
  for (int i = 0; i < 64; ++i) {
    s += part[i * 128 + col];
    s2 += part2[i * 128 + col];
  }
  float mean = s / 32768.0f;
  float var = s2 / 32768.0f - mean * mean;
  float invstd = 1.0f / sqrtf(var + 1e-5f);
  stat[col] = mean;
  stat[128 + col] = invstd;
}

// ---------------- BN apply + exact GELU (in place on h) ----------------
__global__ __launch_bounds__(256) void bngelu_kernel(float* __restrict__ h,
                                                     const float* __restrict__ stat,
                                                     const float* __restrict__ gamma,
                                                     const float* __restrict__ beta) {
  int base = blockIdx.x * 2048 + threadIdx.x;
#pragma unroll
  for (int t = 0; t < 8; ++t) {
    int g = base + t * 256;
    int col = g & 127;
    float v = h[g];
    float z = (v - stat[col]) * stat[128 + col];
    z = z * gamma[col] + beta[col];
    float ge = 0.5f * z * (1.0f + erff(z * 0.70710678118654752440f));
    h[g] = ge;
  }
}

// ---------------- deterministic FPS, one block per cloud ----------------
// Two-phase 32-bit selection (bit-identical to the r5-verified packed-key
// semantics): (A) D = max nd  (floats >= 0: uint-monotone), (B) widx =
// min{idx : nd == D}. Kills all u64 cmp/select/bpermute machinery.
// Wave reduce = 6 DPP levels (row_shr 1/2/4/8 + row_bcast 15/31), pure
// VALU, no LDS-pipe latency. Distinct per-wave slots, zero atomics; the
// two barriers alternate slotD/slotI so no double-buffering is needed.
// Positions in LDS (float2 xy + z); only dd[8] lives in registers.
#define UMAXU(a, b) (((a) > (b)) ? (a) : (b))
#define UMINU(a, b) (((a) < (b)) ? (a) : (b))
#define DPP_FMAX(m, CTRL)                                                       \
  {                                                                             \
    int t_ = __builtin_amdgcn_update_dpp(__float_as_int(m), __float_as_int(m),  \
                                         (CTRL), 0xf, 0xf, false);              \
    m = fmaxf(m, __int_as_float(t_));                                           \
  }
#define DPP_UMIN(c, CTRL)                                                       \
  {                                                                             \
    unsigned int t_ = (unsigned int)__builtin_amdgcn_update_dpp(                \
        (int)(c), (int)(c), (CTRL), 0xf, 0xf, false);                           \
    c = UMINU(c, t_);                                                           \
  }
#define FPS_DIST(i)                                                             \
  {                                                                             \
    const int n = tid + (i) * 1024;                                             \
    float2 xy = lpxy[n];                                                        \
    float zz = lpz[n];                                                          \
    float dx = __fsub_rn(xy.x, lx), dy = __fsub_rn(xy.y, ly),                   \
          dz = __fsub_rn(zz, lz);                                               \
    float d = fmaf(dz, dz, fmaf(dx, dx, __fmul_rn(dy, dy)));                    \
    float nd = fminf(dd##i, d);                                                 \
    dd##i = nd;                                                                 \
    m = fmaxf(m, nd);                                                           \
  }
#define FPS_MATCH(i)                                                            \
  ci = (dd##i == D) ? (unsigned int)(tid + (i) * 1024) : ci;

__global__ __launch_bounds__(1024)
__attribute__((amdgpu_waves_per_eu(4, 4)))
void fps_kernel(const float* __restrict__ pos,
                int* __restrict__ samp,
                float* __restrict__ out) {
  const int b = blockIdx.x;
  const int tid = threadIdx.x;
  const int wv = tid >> 6;  // wave 0..15
  const float* p = pos + b * NPER * 3;
  __shared__ float2 lpxy[NPER];                   // 64 KB
  __shared__ float lpz[NPER];                     // 32 KB
  __shared__ __align__(16) unsigned int slotD[16];
  __shared__ __align__(16) unsigned int slotI[16];
  for (int i = tid; i < NPER; i += 1024) {
    lpxy[i] = make_float2(p[i * 3 + 0], p[i * 3 + 1]);
    lpz[i] = p[i * 3 + 2];
  }
  float dd0, dd1, dd2, dd3, dd4, dd5, dd6, dd7;
  dd0 = dd1 = dd2 = dd3 = dd4 = dd5 = dd6 = dd7 = INFINITY;
  float lx = p[0], ly = p[1], lz = p[2];
  if (tid == 0) {
    samp[b * MPER] = 0;
    out[NEWPOS_OFF + (b * MPER) * 3 + 0] = lx;
    out[NEWPOS_OFF + (b * MPER) * 3 + 1] = ly;
    out[NEWPOS_OFF + (b * MPER) * 3 + 2] = lz;
  }
  __syncthreads();
  for (int s = 1; s < MPER; ++s) {
    // ---- phase A: max distance (float, >= 0) ----
    float m = 0.0f;
    FPS_DIST(0) FPS_DIST(1) FPS_DIST(2) FPS_DIST(3)
    FPS_DIST(4) FPS_DIST(5) FPS_DIST(6) FPS_DIST(7)
    DPP_FMAX(m, 0x111)  // row_shr:1
    DPP_FMAX(m, 0x112)  // row_shr:2
    DPP_FMAX(m, 0x114)  // row_shr:4
    DPP_FMAX(m, 0x118)  // row_shr:8
    DPP_FMAX(m, 0x142)  // row_bcast:15
    DPP_FMAX(m, 0x143)  // row_bcast:31 -> lane 63 has wave max
    if ((tid & 63) == 63) slotD[wv] = __float_as_uint(m);
    __syncthreads();
    const uint4* spD = (const uint4*)slotD;  // broadcast reads
    uint4 a0 = spD[0], a1 = spD[1], a2 = spD[2], a3 = spD[3];
    unsigned int r0 = UMAXU(UMAXU(a0.x, a0.y), UMAXU(a0.z, a0.w));
    unsigned int r1 = UMAXU(UMAXU(a1.x, a1.y), UMAXU(a1.z, a1.w));
    unsigned int r2 = UMAXU(UMAXU(a2.x, a2.y), UMAXU(a2.z, a2.w));
    unsigned int r3 = UMAXU(UMAXU(a3.x, a3.y), UMAXU(a3.z, a3.w));
    const float D = __uint_as_float(UMAXU(UMAXU(r0, r1), UMAXU(r2, r3)));
    // ---- phase B: min index with nd == D ----
    unsigned int ci = 0xFFFFFFFFu;
    FPS_MATCH(7) FPS_MATCH(6) FPS_MATCH(5) FPS_MATCH(4)
    FPS_MATCH(3) FPS_MATCH(2) FPS_MATCH(1) FPS_MATCH(0)  // descending: j=0 wins
    DPP_UMIN(ci, 0x111)
    DPP_UMIN(ci, 0x112)
    DPP_UMIN(ci, 0x114)
    DPP_UMIN(ci, 0x118)
    DPP_UMIN(ci, 0x142)
    DPP_UMIN(ci, 0x143)
    if ((tid & 63) == 63) slotI[wv] = ci;
    __syncthreads();
    const uint4* spI = (const uint4*)slotI;  // broadcast reads
    uint4 b0 = spI[0], b1 = spI[1], b2 = spI[2], b3 = spI[3];
    unsigned int i0 = UMINU(UMINU(b0.x, b0.y), UMINU(b0.z, b0.w));
    unsigned int i1 = UMINU(UMINU(b1.x, b1.y), UMINU(b1.z, b1.w));
    unsigned int i2 = UMINU(UMINU(b2.x, b2.y), UMINU(b2.z, b2.w));
    unsigned int i3 = UMINU(UMINU(b3.x, b3.y), UMINU(b3.z, b3.w));
    const int widx = (int)UMINU(UMINU(i0, i1), UMINU(i2, i3));
    // winner xyz: same-address broadcast LDS reads
    float2 wxy = lpxy[widx];
    float wz = lpz[widx];
    lx = wxy.x; ly = wxy.y; lz = wz;
    if (tid == 0) {
      samp[b * MPER + s] = widx;
      out[NEWPOS_OFF + (b * MPER + s) * 3 + 0] = lx;
      out[NEWPOS_OFF + (b * MPER + s) * 3 + 1] = ly;
      out[NEWPOS_OFF + (b * MPER + s) * 3 + 2] = lz;
    }
    // slotD rewrite (next step, before bar1') is after bar2 of this step;
    // slotI rewrite is after bar1' -> reads and writes never race.
  }
}

// ---------------- kNN: Eigen-style ascending fma dot, expand-formula d2 ----------------
__global__ __launch_bounds__(256) void knn_kernel(const float* __restrict__ pos,
                                                  const float* __restrict__ sqp,
                                                  const int* __restrict__ samp,
                                                  const float* __restrict__ h,
                                                  float* __restrict__ out) {
  const int q = blockIdx.x;
  const int b = q >> 12;
  const int tid = threadIdx.x;
  const int gbase = b * NPER;
  __shared__ float dist[NPER];  // 32 KB
  __shared__ unsigned long long slot[2];
  __shared__ int nbr[16];
  const int sidx = samp[q];
  const float qx = pos[(gbase + sidx) * 3 + 0];
  const float qy = pos[(gbase + sidx) * 3 + 1];
  const float qz = pos[(gbase + sidx) * 3 + 2];
  const float sqq = sqp[gbase + sidx];
  if (tid == 0) {
    slot[0] = ~0ull;
    slot[1] = ~0ull;
  }
  unsigned long long lkey = ~0ull;
  for (int i = 0; i < 32; ++i) {
    int n = tid + i * 256;
    int g = gbase + n;
    // Eigen gebp: fma(q2,p2, fma(q1,p1, rn(q0*p0)))
    float dot = fmaf(qz, pos[g * 3 + 2],
                     fmaf(qy, pos[g * 3 + 1], __fmul_rn(qx, pos[g * 3 + 0])));
    // (sq_q + sq_p) - 2*dot, each op rounded
    float d2 = __fsub_rn(__fadd_rn(sqq, sqp[g]), __fmul_rn(2.0f, dot));
    dist[n] = d2;
    unsigned int ub = __float_as_uint(d2);
    ub = (ub & 0x80000000u) ? ~ub : (ub | 0x80000000u);  // monotone float->uint
    unsigned long long key = ((unsigned long long)ub << 32) | (unsigned int)n;
    lkey = (key < lkey) ? key : lkey;
  }
  __syncthreads();
  for (int r = 0; r < 16; ++r) {
    unsigned long long wk = lkey;
#pragma unroll
    for (int off = 1; off < 64; off <<= 1) {
      unsigned long long o = __shfl_xor(wk, off, 64);
      wk = (o < wk) ? o : wk;
    }
    if ((tid & 63) == 0) atomicMin(&slot[r & 1], wk);
    __syncthreads();
    unsigned long long w = slot[r & 1];
    int n = (int)(unsigned int)(w & 0xFFFFFFFFull);
    if (tid == 0) {
      nbr[r] = n;
      slot[(r & 1) ^ 1] = ~0ull;
    }
    if (tid == (n & 255)) {  // owner removes it and refreshes its local min
      dist[n] = INFINITY;
      lkey = ~0ull;
      for (int i = 0; i < 32; ++i) {
        int nn = tid + i * 256;
        unsigned int ub = __float_as_uint(dist[nn]);
        ub = (ub & 0x80000000u) ? ~ub : (ub | 0x80000000u);
        unsigned long long kk = ((unsigned long long)ub << 32) | (unsigned int)nn;
        lkey = (kk < lkey) ? kk : lkey;
      }
    }
    __syncthreads();
  }
  if (tid < COUT) {
    float mx = -INFINITY;
#pragma unroll
    for (int r = 0; r < 16; ++r) mx = fmaxf(mx, h[(gbase + nbr[r]) * 128 + tid]);
    out[q * 128 + tid] = mx;
  }
}

extern "C" void kernel_launch(void* const* d_in, const int* in_sizes, int n_in,
                              void* d_out, int out_size, void* d_ws, size_t ws_size,
                              hipStream_t stream) {
  (void)in_sizes; (void)n_in; (void)out_size; (void)ws_size;
  const float* x     = (const float*)d_in[0];
  const float* pos   = (const float*)d_in[1];
  const float* W     = (const float*)d_in[3];
  const float* bias  = (const float*)d_in[4];
  const float* gamma = (const float*)d_in[5];
  const float* beta  = (const float*)d_in[6];
  float* out = (float*)d_out;
  char* ws = (char*)d_ws;
  float* h     = (float*)(ws + WS_H);
  float* sqp   = (float*)(ws + WS_SQP);
  int*   samp  = (int*)(ws + WS_SAMP);
  float* part  = (float*)(ws + WS_PART);
  float* part2 = (float*)(ws + WS_PART2);
  float* stat  = (float*)(ws + WS_STAT);

  misc_kernel<<<dim3(32), dim3(1024), 0, stream>>>(pos, sqp, out);
  matmul_kernel<<<dim3(2048), dim3(256), 0, stream>>>(x, W, bias, h);
  stats_kernel<<<dim3(64), dim3(256), 0, stream>>>(h, part, part2);
  finalize_kernel<<<dim3(1), dim3(128), 0, stream>>>(part, part2, stat);
  bngelu_kernel<<<dim3(2048), dim3(256), 0, stream>>>(h, stat, gamma, beta);
  fps_kernel<<<dim3(NB), dim3(1024), 0, stream>>>(pos, samp, out);
  knn_kernel<<<dim3(MTOT), dim3(256), 0, stream>>>(pos, sqp, samp, h, out);
}

// Round 17
// 4616.611 us; speedup vs baseline: 1.3718x; 1.0567x over previous
//
#include <hip/hip_runtime.h>
#include <math.h>

#define NB    4
#define NPER  8192
#define MPER  4096
#define NTOT  32768
#define MTOT  16384
#define COUT  128

// d_out layout (floats): new_x [16384*128] | new_pos [16384*3] | new_batch [16384]
#define NEWPOS_OFF 2097152
#define NEWB_OFF   2146304

// workspace layout (bytes); ~17 MB
#define WS_H     0u           // 32768*128*4 = 16777216
#define WS_SQP   16777216u    // 32768*4
#define WS_SAMP  16908288u    // 16384*4
#define WS_PART  16973824u    // 64*128*4
#define WS_PART2 17006592u    // 64*128*4
#define WS_STAT  17039360u    // 256*4

// ---------------- sq_p + new_batch ----------------
// XLA:CPU fast-math emission of sum(p*p, -1): fma(z,z, fma(x,x, y*y)).
__global__ void misc_kernel(const float* __restrict__ pos, float* __restrict__ sqp,
                            float* __restrict__ out) {
  int g = blockIdx.x * 1024 + threadIdx.x;
  if (g < NTOT) {
    float x = pos[g * 3 + 0], y = pos[g * 3 + 1], z = pos[g * 3 + 2];
    sqp[g] = fmaf(z, z, fmaf(x, x, __fmul_rn(y, y)));
  }
  if (g < MTOT) out[NEWB_OFF + g] = (float)(g >> 12);
}

// ---------------- h_pre = x @ W  (+b) ----------------
__global__ __launch_bounds__(256) void matmul_kernel(const float* __restrict__ x,
                                                     const float* __restrict__ W,
                                                     const float* __restrict__ bias,
                                                     float* __restrict__ h) {
  __shared__ float xs[16][64];
  const int tid = threadIdx.x;
  const int rowbase = blockIdx.x * 16;
  for (int i = tid; i < 16 * 64; i += 256) xs[i >> 6][i & 63] = x[rowbase * 64 + i];
  __syncthreads();
  const int col = tid & 127;
  const int rs = (tid >> 7) * 8;
  float acc[8] = {0.f, 0.f, 0.f, 0.f, 0.f, 0.f, 0.f, 0.f};
  for (int k = 0; k < 64; ++k) {
    float wv = W[k * 128 + col];
#pragma unroll
    for (int r = 0; r < 8; ++r) acc[r] = fmaf(xs[rs + r][k], wv, acc[r]);
  }
  float bb = bias[col];
#pragma unroll
  for (int r = 0; r < 8; ++r) h[(rowbase + rs + r) * 128 + col] = acc[r] + bb;
}

// ---------------- BN partial sums (deterministic tree) ----------------
__global__ __launch_bounds__(256) void stats_kernel(const float* __restrict__ h,
                                                    float* __restrict__ part,
                                                    float* __restrict__ part2) {
  const int tid = threadIdx.x;
  const int col = tid & 127;
  const int half = tid >> 7;
  const int r0 = blockIdx.x * 512;
  float s = 0.f, s2 = 0.f;
  for (int r = r0 + half; r < r0 + 512; r += 2) {
    float v = h[r * 128 + col];
    s += v;
    s2 = fmaf(v, v, s2);
  }
  __shared__ float ps[2][128], ps2[2][128];
  ps[half][col] = s;
  ps2[half][col] = s2;
  __syncthreads();
  if (half == 0) {
    part[blockIdx.x * 128 + col] = ps[0][col] + ps[1][col];
    part2[blockIdx.x * 128 + col] = ps2[0][col] + ps2[1][col];
  }
}

__global__ void finalize_kernel(const float* __restrict__ part,
                                const float* __restrict__ part2,
                                float* __restrict__ stat) {
  int col = threadIdx.x;  // 128 threads
  float s = 0.f, s2 = 0.f;
  for (int i = 0; i < 64; ++i) {
    s += part[i * 128 + col];
    s2 += part2[i * 128 + col];
  }
  float mean = s / 32768.0f;
  float var = s2 / 32768.0f - mean * mean;
  float invstd = 1.0f / sqrtf(var + 1e-5f);
  stat[col] = mean;
  stat[128 + col] = invstd;
}

// ---------------- BN apply + exact GELU (in place on h) ----------------
__global__ __launch_bounds__(256) void bngelu_kernel(float* __restrict__ h,
                                                     const float* __restrict__ stat,
                                                     const float* __restrict__ gamma,
                                                     const float* __restrict__ beta) {
  int base = blockIdx.x * 2048 + threadIdx.x;
#pragma unroll
  for (int t = 0; t < 8; ++t) {
    int g = base + t * 256;
    int col = g & 127;
    float v = h[g];
    float z = (v - stat[col]) * stat[128 + col];
    z = z * gamma[col] + beta[col];
    float ge = 0.5f * z * (1.0f + erff(z * 0.70710678118654752440f));
    h[g] = ge;
  }
}

// ---------------- deterministic FPS, one block per cloud ----------------
// r16's two-phase 32-bit DPP selection + register-resident points:
//  - dist phase reads positions from REGISTERS (8 pts/thread named scalars,
//    pins, waves_per_eu(4,4) so the RA has no occupancy reward for
//    spilling) -> zero LDS-pipe traffic in the hot phase (r16 spent
//    ~1500-2000 cyc/step on 256 LDS wave-instructions/CU).
//  - selection: (A) D = max nd via 6 DPP fmax levels; (B) widx =
//    min{idx : dd == D} via 6 DPP umin levels. Distinct per-wave 32-bit
//    slots, zero atomics, two barriers (bit-identical semantics to the
//    r5-verified packed-key: max dist, tie -> lowest index).
//  - LDS keeps a position copy ONLY for the once-per-step winner-xyz
//    same-address broadcast read (free).
#define UMAXU(a, b) (((a) > (b)) ? (a) : (b))
#define UMINU(a, b) (((a) < (b)) ? (a) : (b))
#define DPP_FMAX(m, CTRL)                                                       \
  {                                                                             \
    int t_ = __builtin_amdgcn_update_dpp(__float_as_int(m), __float_as_int(m),  \
                                         (CTRL), 0xf, 0xf, false);              \
    m = fmaxf(m, __int_as_float(t_));                                           \
  }
#define DPP_UMIN(c, CTRL)                                                       \
  {                                                                             \
    unsigned int t_ = (unsigned int)__builtin_amdgcn_update_dpp(                \
        (int)(c), (int)(c), (CTRL), 0xf, 0xf, false);                           \
    c = UMINU(c, t_);                                                           \
  }
#define FPS_DECL(i) float px##i, py##i, pz##i, dd##i;
#define FPS_LOAD(i)                     \
  {                                     \
    const int n = tid + (i) * 1024;     \
    px##i = p[n * 3 + 0];               \
    py##i = p[n * 3 + 1];               \
    pz##i = p[n * 3 + 2];               \
    dd##i = INFINITY;                   \
    lpxy[n] = make_float2(px##i, py##i);\
    lpz[n] = pz##i;                     \
  }
#define FPS_PIN(i) \
  asm volatile("" : "+v"(px##i), "+v"(py##i), "+v"(pz##i));
#define FPS_DIST(i)                                                             \
  {                                                                             \
    float dx = __fsub_rn(px##i, lx), dy = __fsub_rn(py##i, ly),                 \
          dz = __fsub_rn(pz##i, lz);                                            \
    float d = fmaf(dz, dz, fmaf(dx, dx, __fmul_rn(dy, dy)));                    \
    float nd = fminf(dd##i, d);                                                 \
    dd##i = nd;                                                                 \
    m = fmaxf(m, nd);                                                           \
  }
#define FPS_MATCH(i)                                                            \
  ci = (dd##i == D) ? (unsigned int)(tid + (i) * 1024) : ci;

__global__ __launch_bounds__(1024)
__attribute__((amdgpu_waves_per_eu(4, 4)))
void fps_kernel(const float* __restrict__ pos,
                int* __restrict__ samp,
                float* __restrict__ out) {
  const int b = blockIdx.x;
  const int tid = threadIdx.x;
  const int wv = tid >> 6;  // wave 0..15
  const float* p = pos + b * NPER * 3;
  __shared__ float2 lpxy[NPER];                   // 64 KB (winner lookup only)
  __shared__ float lpz[NPER];                     // 32 KB
  __shared__ __align__(16) unsigned int slotD[16];
  __shared__ __align__(16) unsigned int slotI[16];
  FPS_DECL(0) FPS_DECL(1) FPS_DECL(2) FPS_DECL(3)
  FPS_DECL(4) FPS_DECL(5) FPS_DECL(6) FPS_DECL(7)
  FPS_LOAD(0) FPS_LOAD(1) FPS_LOAD(2) FPS_LOAD(3)
  FPS_LOAD(4) FPS_LOAD(5) FPS_LOAD(6) FPS_LOAD(7)
  FPS_PIN(0) FPS_PIN(1) FPS_PIN(2) FPS_PIN(3)
  FPS_PIN(4) FPS_PIN(5) FPS_PIN(6) FPS_PIN(7)
  float lx = p[0], ly = p[1], lz = p[2];
  if (tid == 0) {
    samp[b * MPER] = 0;
    out[NEWPOS_OFF + (b * MPER) * 3 + 0] = lx;
    out[NEWPOS_OFF + (b * MPER) * 3 + 1] = ly;
    out[NEWPOS_OFF + (b * MPER) * 3 + 2] = lz;
  }
  __syncthreads();
  for (int s = 1; s < MPER; ++s) {
    // ---- phase A: max distance (float, >= 0) ----
    float m = 0.0f;
    FPS_DIST(0) FPS_DIST(1) FPS_DIST(2) FPS_DIST(3)
    FPS_DIST(4) FPS_DIST(5) FPS_DIST(6) FPS_DIST(7)
    DPP_FMAX(m, 0x111)  // row_shr:1
    DPP_FMAX(m, 0x112)  // row_shr:2
    DPP_FMAX(m, 0x114)  // row_shr:4
    DPP_FMAX(m, 0x118)  // row_shr:8
    DPP_FMAX(m, 0x142)  // row_bcast:15
    DPP_FMAX(m, 0x143)  // row_bcast:31 -> lane 63 has wave max
    if ((tid & 63) == 63) slotD[wv] = __float_as_uint(m);
    __syncthreads();
    const uint4* spD = (const uint4*)slotD;  // broadcast reads
    uint4 a0 = spD[0], a1 = spD[1], a2 = spD[2], a3 = spD[3];
    unsigned int r0 = UMAXU(UMAXU(a0.x, a0.y), UMAXU(a0.z, a0.w));
    unsigned int r1 = UMAXU(UMAXU(a1.x, a1.y), UMAXU(a1.z, a1.w));
    unsigned int r2 = UMAXU(UMAXU(a2.x, a2.y), UMAXU(a2.z, a2.w));
    unsigned int r3 = UMAXU(UMAXU(a3.x, a3.y), UMAXU(a3.z, a3.w));
    const float D = __uint_as_float(UMAXU(UMAXU(r0, r1), UMAXU(r2, r3)));
    // ---- phase B: min index with nd == D ----
    unsigned int ci = 0xFFFFFFFFu;
    FPS_MATCH(7) FPS_MATCH(6) FPS_MATCH(5) FPS_MATCH(4)
    FPS_MATCH(3) FPS_MATCH(2) FPS_MATCH(1) FPS_MATCH(0)  // descending: j=0 wins
    DPP_UMIN(ci, 0x111)
    DPP_UMIN(ci, 0x112)
    DPP_UMIN(ci, 0x114)
    DPP_UMIN(ci, 0x118)
    DPP_UMIN(ci, 0x142)
    DPP_UMIN(ci, 0x143)
    if ((tid & 63) == 63) slotI[wv] = ci;
    __syncthreads();
    const uint4* spI = (const uint4*)slotI;  // broadcast reads
    uint4 b0 = spI[0], b1 = spI[1], b2 = spI[2], b3 = spI[3];
    unsigned int i0 = UMINU(UMINU(b0.x, b0.y), UMINU(b0.z, b0.w));
    unsigned int i1 = UMINU(UMINU(b1.x, b1.y), UMINU(b1.z, b1.w));
    unsigned int i2 = UMINU(UMINU(b2.x, b2.y), UMINU(b2.z, b2.w));
    unsigned int i3 = UMINU(UMINU(b3.x, b3.y), UMINU(b3.z, b3.w));
    const int widx = (int)UMINU(UMINU(i0, i1), UMINU(i2, i3));
    // winner xyz: same-address broadcast LDS reads
    float2 wxy = lpxy[widx];
    float wz = lpz[widx];
    lx = wxy.x; ly = wxy.y; lz = wz;
    if (tid == 0) {
      samp[b * MPER + s] = widx;
      out[NEWPOS_OFF + (b * MPER + s) * 3 + 0] = lx;
      out[NEWPOS_OFF + (b * MPER + s) * 3 + 1] = ly;
      out[NEWPOS_OFF + (b * MPER + s) * 3 + 2] = lz;
    }
    // slotD rewrite (next step) is ordered after this step's barrier #2;
    // slotI rewrite after next step's barrier #1 -> no read/write races.
  }
}

// ---------------- kNN: Eigen-style ascending fma dot, expand-formula d2 ----------------
__global__ __launch_bounds__(256) void knn_kernel(const float* __restrict__ pos,
                                                  const float* __restrict__ sqp,
                                                  const int* __restrict__ samp,
                                                  const float* __restrict__ h,
                                                  float* __restrict__ out) {
  const int q = blockIdx.x;
  const int b = q >> 12;
  const int tid = threadIdx.x;
  const int gbase = b * NPER;
  __shared__ float dist[NPER];  // 32 KB
  __shared__ unsigned long long slot[2];
  __shared__ int nbr[16];
  const int sidx = samp[q];
  const float qx = pos[(gbase + sidx) * 3 + 0];
  const float qy = pos[(gbase + sidx) * 3 + 1];
  const float qz = pos[(gbase + sidx) * 3 + 2];
  const float sqq = sqp[gbase + sidx];
  if (tid == 0) {
    slot[0] = ~0ull;
    slot[1] = ~0ull;
  }
  unsigned long long lkey = ~0ull;
  for (int i = 0; i < 32; ++i) {
    int n = tid + i * 256;
    int g = gbase + n;
    // Eigen gebp: fma(q2,p2, fma(q1,p1, rn(q0*p0)))
    float dot = fmaf(qz, pos[g * 3 + 2],
                     fmaf(qy, pos[g * 3 + 1], __fmul_rn(qx, pos[g * 3 + 0])));
    // (sq_q + sq_p) - 2*dot, each op rounded
    float d2 = __fsub_rn(__fadd_rn(sqq, sqp[g]), __fmul_rn(2.0f, dot));
    dist[n] = d2;
    unsigned int ub = __float_as_uint(d2);
    ub = (ub & 0x80000000u) ? ~ub : (ub | 0x80000000u);  // monotone float->uint
    unsigned long long key = ((unsigned long long)ub << 32) | (unsigned int)n;
    lkey = (key < lkey) ? key : lkey;
  }
  __syncthreads();
  for (int r = 0; r < 16; ++r) {
    unsigned long long wk = lkey;
#pragma unroll
    for (int off = 1; off < 64; off <<= 1) {
      unsigned long long o = __shfl_xor(wk, off, 64);
      wk = (o < wk) ? o : wk;
    }
    if ((tid & 63) == 0) atomicMin(&slot[r & 1], wk);
    __syncthreads();
    unsigned long long w = slot[r & 1];
    int n = (int)(unsigned int)(w & 0xFFFFFFFFull);
    if (tid == 0) {
      nbr[r] = n;
      slot[(r & 1) ^ 1] = ~0ull;
    }
    if (tid == (n & 255)) {  // owner removes it and refreshes its local min
      dist[n] = INFINITY;
      lkey = ~0ull;
      for (int i = 0; i < 32; ++i) {
        int nn = tid + i * 256;
        unsigned int ub = __float_as_uint(dist[nn]);
        ub = (ub & 0x80000000u) ? ~ub : (ub | 0x80000000u);
        unsigned long long kk = ((unsigned long long)ub << 32) | (unsigned int)nn;
        lkey = (kk < lkey) ? kk : lkey;
      }
    }
    __syncthreads();
  }
  if (tid < COUT) {
    float mx = -INFINITY;
#pragma unroll
    for (int r = 0; r < 16; ++r) mx = fmaxf(mx, h[(gbase + nbr[r]) * 128 + tid]);
    out[q * 128 + tid] = mx;
  }
}

extern "C" void kernel_launch(void* const* d_in, const int* in_sizes, int n_in,
                              void* d_out, int out_size, void* d_ws, size_t ws_size,
                              hipStream_t stream) {
  (void)in_sizes; (void)n_in; (void)out_size; (void)ws_size;
  const float* x     = (const float*)d_in[0];
  const float* pos   = (const float*)d_in[1];
  const float* W     = (const float*)d_in[3];
  const float* bias  = (const float*)d_in[4];
  const float* gamma = (const float*)d_in[5];
  const float* beta  = (const float*)d_in[6];
  float* out = (float*)d_out;
  char* ws = (char*)d_ws;
  float* h     = (float*)(ws + WS_H);
  float* sqp   = (float*)(ws + WS_SQP);
  int*   samp  = (int*)(ws + WS_SAMP);
  float* part  = (float*)(ws + WS_PART);
  float* part2 = (float*)(ws + WS_PART2);
  float* stat  = (float*)(ws + WS_STAT);

  misc_kernel<<<dim3(32), dim3(1024), 0, stream>>>(pos, sqp, out);
  matmul_kernel<<<dim3(2048), dim3(256), 0, stream>>>(x, W, bias, h);
  stats_kernel<<<dim3(64), dim3(256), 0, stream>>>(h, part, part2);
  finalize_kernel<<<dim3(1), dim3(128), 0, stream>>>(part, part2, stat);
  bngelu_kernel<<<dim3(2048), dim3(256), 0, stream>>>(h, stat, gamma, beta);
  fps_kernel<<<dim3(NB), dim3(1024), 0, stream>>>(pos, samp, out);
  knn_kernel<<<dim3(MTOT), dim3(256), 0, stream>>>(pos, sqp, samp, h, out);
}

// Round 18
// 3743.364 us; speedup vs baseline: 1.6918x; 1.2333x over previous
//
#include <hip/hip_runtime.h>
#include <math.h>

#define NB    4
#define NPER  8192
#define MPER  4096
#define NTOT  32768
#define MTOT  16384
#define COUT  128

// d_out layout (floats): new_x [16384*128] | new_pos [16384*3] | new_batch [16384]
#define NEWPOS_OFF 2097152
#define NEWB_OFF   2146304

// workspace layout (bytes); ~17 MB
#define WS_H     0u           // 32768*128*4 = 16777216
#define WS_SQP   16777216u    // 32768*4
#define WS_SAMP  16908288u    // 16384*4
#define WS_PART  16973824u    // 64*128*4
#define WS_PART2 17006592u    // 64*128*4
#define WS_STAT  17039360u    // 256*4

// ---------------- sq_p + new_batch ----------------
// XLA:CPU fast-math emission of sum(p*p, -1): fma(z,z, fma(x,x, y*y)).
__global__ void misc_kernel(const float* __restrict__ pos, float* __restrict__ sqp,
                            float* __restrict__ out) {
  int g = blockIdx.x * 1024 + threadIdx.x;
  if (g < NTOT) {
    float x = pos[g * 3 + 0], y = pos[g * 3 + 1], z = pos[g * 3 + 2];
    sqp[g] = fmaf(z, z, fmaf(x, x, __fmul_rn(y, y)));
  }
  if (g < MTOT) out[NEWB_OFF + g] = (float)(g >> 12);
}

// ---------------- h_pre = x @ W  (+b) ----------------
__global__ __launch_bounds__(256) void matmul_kernel(const float* __restrict__ x,
                                                     const float* __restrict__ W,
                                                     const float* __restrict__ bias,
                                                     float* __restrict__ h) {
  __shared__ float xs[16][64];
  const int tid = threadIdx.x;
  const int rowbase = blockIdx.x * 16;
  for (int i = tid; i < 16 * 64; i += 256) xs[i >> 6][i & 63] = x[rowbase * 64 + i];
  __syncthreads();
  const int col = tid & 127;
  const int rs = (tid >> 7) * 8;
  float acc[8] = {0.f, 0.f, 0.f, 0.f, 0.f, 0.f, 0.f, 0.f};
  for (int k = 0; k < 64; ++k) {
    float wv = W[k * 128 + col];
#pragma unroll
    for (int r = 0; r < 8; ++r) acc[r] = fmaf(xs[rs + r][k], wv, acc[r]);
  }
  float bb = bias[col];
#pragma unroll
  for (int r = 0; r < 8; ++r) h[(rowbase + rs + r) * 128 + col] = acc[r] + bb;
}

// ---------------- BN partial sums (deterministic tree) ----------------
__global__ __launch_bounds__(256) void stats_kernel(const float* __restrict__ h,
                                                    float* __restrict__ part,
                                                    float* __restrict__ part2) {
  const int tid = threadIdx.x;
  const int col = tid & 127;
  const int half = tid >> 7;
  const int r0 = blockIdx.x * 512;
  float s = 0.f, s2 = 0.f;
  for (int r = r0 + half; r < r0 + 512; r += 2) {
    float v = h[r * 128 + col];
    s += v;
    s2 = fmaf(v, v, s2);
  }
  __shared__ float ps[2][128], ps2[2][128];
  ps[half][col] = s;
  ps2[half][col] = s2;
  __syncthreads();
  if (half == 0) {
    part[blockIdx.x * 128 + col] = ps[0][col] + ps[1][col];
    part2[blockIdx.x * 128 + col] = ps2[0][col] + ps2[1][col];
  }
}

__global__ void finalize_kernel(const float* __restrict__ part,
                                const float* __restrict__ part2,
                                float* __restrict__ stat) {
  int col = threadIdx.x;  // 128 threads
  float s = 0.f, s2 = 0.f;
  for (int i = 0; i < 64; ++i) {
    s += part[i * 128 + col];
    s2 += part2[i * 128 + col];
  }
  float mean = s / 32768.0f;
  float var = s2 / 32768.0f - mean * mean;
  float invstd = 1.0f / sqrtf(var + 1e-5f);
  stat[col] = mean;
  stat[128 + col] = invstd;
}

// ---------------- BN apply + exact GELU (in place on h) ----------------
__global__ __launch_bounds__(256) void bngelu_kernel(float* __restrict__ h,
                                                     const float* __restrict__ stat,
                                                     const float* __restrict__ gamma,
                                                     const float* __restrict__ beta) {
  int base = blockIdx.x * 2048 + threadIdx.x;
#pragma unroll
  for (int t = 0; t < 8; ++t) {
    int g = base + t * 256;
    int col = g & 127;
    float v = h[g];
    float z = (v - stat[col]) * stat[128 + col];
    z = z * gamma[col] + beta[col];
    float ge = 0.5f * z * (1.0f + erff(z * 0.70710678118654752440f));
    h[g] = ge;
  }
}

// ---------------- deterministic FPS, one block per cloud ----------------
// Combination of the two independently-proven wins:
//  - REGISTER-RESIDENT point cache: 512 threads x 16 pts/thread named
//    scalars + pins + waves_per_eu(2,2). r13 is the only config where the
//    RA actually allocated ~88 VGPR (resident); 1024-thread variants
//    (r10/r11/r17) all spilled to 52 VGPR regardless of budget.
//  - CHEAP SELECTION (r16/r17): two-phase 32-bit, (A) D = max nd via 6 DPP
//    fmax levels, (B) widx = min{idx : dd == D} via 6 DPP umin levels;
//    distinct per-wave 32-bit slots, zero atomics, zero bpermute, two
//    barriers. Bit-identical semantics to the r5-verified packed-key
//    (max dist, tie -> lowest index).
//  - LDS position copy used ONLY for the once-per-step winner-xyz
//    same-address broadcast read (free).
#define UMAXU(a, b) (((a) > (b)) ? (a) : (b))
#define UMINU(a, b) (((a) < (b)) ? (a) : (b))
#define DPP_FMAX(m, CTRL)                                                       \
  {                                                                             \
    int t_ = __builtin_amdgcn_update_dpp(__float_as_int(m), __float_as_int(m),  \
                                         (CTRL), 0xf, 0xf, false);              \
    m = fmaxf(m, __int_as_float(t_));                                           \
  }
#define DPP_UMIN(c, CTRL)                                                       \
  {                                                                             \
    unsigned int t_ = (unsigned int)__builtin_amdgcn_update_dpp(                \
        (int)(c), (int)(c), (CTRL), 0xf, 0xf, false);                           \
    c = UMINU(c, t_);                                                           \
  }
#define FPS_DECL(i) float px##i, py##i, pz##i, dd##i;
#define FPS_LOAD(i)                     \
  {                                     \
    const int n = tid + (i) * 512;      \
    px##i = p[n * 3 + 0];               \
    py##i = p[n * 3 + 1];               \
    pz##i = p[n * 3 + 2];               \
    dd##i = INFINITY;                   \
    lpxy[n] = make_float2(px##i, py##i);\
    lpz[n] = pz##i;                     \
  }
#define FPS_PIN(i) \
  asm volatile("" : "+v"(px##i), "+v"(py##i), "+v"(pz##i));
#define FPS_DIST(i)                                                             \
  {                                                                             \
    float dx = __fsub_rn(px##i, lx), dy = __fsub_rn(py##i, ly),                 \
          dz = __fsub_rn(pz##i, lz);                                            \
    float d = fmaf(dz, dz, fmaf(dx, dx, __fmul_rn(dy, dy)));                    \
    float nd = fminf(dd##i, d);                                                 \
    dd##i = nd;                                                                 \
    m = fmaxf(m, nd);                                                           \
  }
#define FPS_MATCH(i)                                                            \
  ci = (dd##i == D) ? (unsigned int)(tid + (i) * 512) : ci;

__global__ __launch_bounds__(512)
__attribute__((amdgpu_waves_per_eu(2, 2)))
void fps_kernel(const float* __restrict__ pos,
                int* __restrict__ samp,
                float* __restrict__ out) {
  const int b = blockIdx.x;
  const int tid = threadIdx.x;
  const int wv = tid >> 6;  // wave 0..7
  const float* p = pos + b * NPER * 3;
  __shared__ float2 lpxy[NPER];                   // 64 KB (winner lookup only)
  __shared__ float lpz[NPER];                     // 32 KB
  __shared__ __align__(16) unsigned int slotD[8];
  __shared__ __align__(16) unsigned int slotI[8];
  FPS_DECL(0) FPS_DECL(1) FPS_DECL(2) FPS_DECL(3)
  FPS_DECL(4) FPS_DECL(5) FPS_DECL(6) FPS_DECL(7)
  FPS_DECL(8) FPS_DECL(9) FPS_DECL(10) FPS_DECL(11)
  FPS_DECL(12) FPS_DECL(13) FPS_DECL(14) FPS_DECL(15)
  FPS_LOAD(0) FPS_LOAD(1) FPS_LOAD(2) FPS_LOAD(3)
  FPS_LOAD(4) FPS_LOAD(5) FPS_LOAD(6) FPS_LOAD(7)
  FPS_LOAD(8) FPS_LOAD(9) FPS_LOAD(10) FPS_LOAD(11)
  FPS_LOAD(12) FPS_LOAD(13) FPS_LOAD(14) FPS_LOAD(15)
  FPS_PIN(0) FPS_PIN(1) FPS_PIN(2) FPS_PIN(3)
  FPS_PIN(4) FPS_PIN(5) FPS_PIN(6) FPS_PIN(7)
  FPS_PIN(8) FPS_PIN(9) FPS_PIN(10) FPS_PIN(11)
  FPS_PIN(12) FPS_PIN(13) FPS_PIN(14) FPS_PIN(15)
  float lx = p[0], ly = p[1], lz = p[2];
  if (tid == 0) {
    samp[b * MPER] = 0;
    out[NEWPOS_OFF + (b * MPER) * 3 + 0] = lx;
    out[NEWPOS_OFF + (b * MPER) * 3 + 1] = ly;
    out[NEWPOS_OFF + (b * MPER) * 3 + 2] = lz;
  }
  __syncthreads();
  for (int s = 1; s < MPER; ++s) {
    // ---- phase A: max distance (float, >= 0) ----
    float m = 0.0f;
    FPS_DIST(0) FPS_DIST(1) FPS_DIST(2) FPS_DIST(3)
    FPS_DIST(4) FPS_DIST(5) FPS_DIST(6) FPS_DIST(7)
    FPS_DIST(8) FPS_DIST(9) FPS_DIST(10) FPS_DIST(11)
    FPS_DIST(12) FPS_DIST(13) FPS_DIST(14) FPS_DIST(15)
    DPP_FMAX(m, 0x111)  // row_shr:1
    DPP_FMAX(m, 0x112)  // row_shr:2
    DPP_FMAX(m, 0x114)  // row_shr:4
    DPP_FMAX(m, 0x118)  // row_shr:8
    DPP_FMAX(m, 0x142)  // row_bcast:15
    DPP_FMAX(m, 0x143)  // row_bcast:31 -> lane 63 has wave max
    if ((tid & 63) == 63) slotD[wv] = __float_as_uint(m);
    __syncthreads();
    const uint4* spD = (const uint4*)slotD;  // broadcast reads
    uint4 a0 = spD[0], a1 = spD[1];
    unsigned int r0 = UMAXU(UMAXU(a0.x, a0.y), UMAXU(a0.z, a0.w));
    unsigned int r1 = UMAXU(UMAXU(a1.x, a1.y), UMAXU(a1.z, a1.w));
    const float D = __uint_as_float(UMAXU(r0, r1));
    // ---- phase B: min index with nd == D ----
    unsigned int ci = 0xFFFFFFFFu;
    FPS_MATCH(15) FPS_MATCH(14) FPS_MATCH(13) FPS_MATCH(12)
    FPS_MATCH(11) FPS_MATCH(10) FPS_MATCH(9) FPS_MATCH(8)
    FPS_MATCH(7) FPS_MATCH(6) FPS_MATCH(5) FPS_MATCH(4)
    FPS_MATCH(3) FPS_MATCH(2) FPS_MATCH(1) FPS_MATCH(0)  // descending: i=0 wins
    DPP_UMIN(ci, 0x111)
    DPP_UMIN(ci, 0x112)
    DPP_UMIN(ci, 0x114)
    DPP_UMIN(ci, 0x118)
    DPP_UMIN(ci, 0x142)
    DPP_UMIN(ci, 0x143)
    if ((tid & 63) == 63) slotI[wv] = ci;
    __syncthreads();
    const uint4* spI = (const uint4*)slotI;  // broadcast reads
    uint4 b0 = spI[0], b1 = spI[1];
    unsigned int i0 = UMINU(UMINU(b0.x, b0.y), UMINU(b0.z, b0.w));
    unsigned int i1 = UMINU(UMINU(b1.x, b1.y), UMINU(b1.z, b1.w));
    const int widx = (int)UMINU(i0, i1);
    // winner xyz: same-address broadcast LDS reads
    float2 wxy = lpxy[widx];
    float wz = lpz[widx];
    lx = wxy.x; ly = wxy.y; lz = wz;
    if (tid == 0) {
      samp[b * MPER + s] = widx;
      out[NEWPOS_OFF + (b * MPER + s) * 3 + 0] = lx;
      out[NEWPOS_OFF + (b * MPER + s) * 3 + 1] = ly;
      out[NEWPOS_OFF + (b * MPER + s) * 3 + 2] = lz;
    }
    // slotD rewrite (next step) is ordered after this step's barrier #2;
    // slotI rewrite after next step's barrier #1 -> no read/write races.
  }
}

// ---------------- kNN: Eigen-style ascending fma dot, expand-formula d2 ----------------
__global__ __launch_bounds__(256) void knn_kernel(const float* __restrict__ pos,
                                                  const float* __restrict__ sqp,
                                                  const int* __restrict__ samp,
                                                  const float* __restrict__ h,
                                                  float* __restrict__ out) {
  const int q = blockIdx.x;
  const int b = q >> 12;
  const int tid = threadIdx.x;
  const int gbase = b * NPER;
  __shared__ float dist[NPER];  // 32 KB
  __shared__ unsigned long long slot[2];
  __shared__ int nbr[16];
  const int sidx = samp[q];
  const float qx = pos[(gbase + sidx) * 3 + 0];
  const float qy = pos[(gbase + sidx) * 3 + 1];
  const float qz = pos[(gbase + sidx) * 3 + 2];
  const float sqq = sqp[gbase + sidx];
  if (tid == 0) {
    slot[0] = ~0ull;
    slot[1] = ~0ull;
  }
  unsigned long long lkey = ~0ull;
  for (int i = 0; i < 32; ++i) {
    int n = tid + i * 256;
    int g = gbase + n;
    // Eigen gebp: fma(q2,p2, fma(q1,p1, rn(q0*p0)))
    float dot = fmaf(qz, pos[g * 3 + 2],
                     fmaf(qy, pos[g * 3 + 1], __fmul_rn(qx, pos[g * 3 + 0])));
    // (sq_q + sq_p) - 2*dot, each op rounded
    float d2 = __fsub_rn(__fadd_rn(sqq, sqp[g]), __fmul_rn(2.0f, dot));
    dist[n] = d2;
    unsigned int ub = __float_as_uint(d2);
    ub = (ub & 0x80000000u) ? ~ub : (ub | 0x80000000u);  // monotone float->uint
    unsigned long long key = ((unsigned long long)ub << 32) | (unsigned int)n;
    lkey = (key < lkey) ? key : lkey;
  }
  __syncthreads();
  for (int r = 0; r < 16; ++r) {
    unsigned long long wk = lkey;
#pragma unroll
    for (int off = 1; off < 64; off <<= 1) {
      unsigned long long o = __shfl_xor(wk, off, 64);
      wk = (o < wk) ? o : wk;
    }
    if ((tid & 63) == 0) atomicMin(&slot[r & 1], wk);
    __syncthreads();
    unsigned long long w = slot[r & 1];
    int n = (int)(unsigned int)(w & 0xFFFFFFFFull);
    if (tid == 0) {
      nbr[r] = n;
      slot[(r & 1) ^ 1] = ~0ull;
    }
    if (tid == (n & 255)) {  // owner removes it and refreshes its local min
      dist[n] = INFINITY;
      lkey = ~0ull;
      for (int i = 0; i < 32; ++i) {
        int nn = tid + i * 256;
        unsigned int ub = __float_as_uint(dist[nn]);
        ub = (ub & 0x80000000u) ? ~ub : (ub | 0x80000000u);
        unsigned long long kk = ((unsigned long long)ub << 32) | (unsigned int)nn;
        lkey = (kk < lkey) ? kk : lkey;
      }
    }
    __syncthreads();
  }
  if (tid < COUT) {
    float mx = -INFINITY;
#pragma unroll
    for (int r = 0; r < 16; ++r) mx = fmaxf(mx, h[(gbase + nbr[r]) * 128 + tid]);
    out[q * 128 + tid] = mx;
  }
}

extern "C" void kernel_launch(void* const* d_in, const int* in_sizes, int n_in,
                              void* d_out, int out_size, void* d_ws, size_t ws_size,
                              hipStream_t stream) {
  (void)in_sizes; (void)n_in; (void)out_size; (void)ws_size;
  const float* x     = (const float*)d_in[0];
  const float* pos   = (const float*)d_in[1];
  const float* W     = (const float*)d_in[3];
  const float* bias  = (const float*)d_in[4];
  const float* gamma = (const float*)d_in[5];
  const float* beta  = (const float*)d_in[6];
  float* out = (float*)d_out;
  char* ws = (char*)d_ws;
  float* h     = (float*)(ws + WS_H);
  float* sqp   = (float*)(ws + WS_SQP);
  int*   samp  = (int*)(ws + WS_SAMP);
  float* part  = (float*)(ws + WS_PART);
  float* part2 = (float*)(ws + WS_PART2);
  float* stat  = (float*)(ws + WS_STAT);

  misc_kernel<<<dim3(32), dim3(1024), 0, stream>>>(pos, sqp, out);
  matmul_kernel<<<dim3(2048), dim3(256), 0, stream>>>(x, W, bias, h);
  stats_kernel<<<dim3(64), dim3(256), 0, stream>>>(h, part, part2);
  finalize_kernel<<<dim3(1), dim3(128), 0, stream>>>(part, part2, stat);
  bngelu_kernel<<<dim3(2048), dim3(256), 0, stream>>>(h, stat, gamma, beta);
  fps_kernel<<<dim3(NB), dim3(512), 0, stream>>>(pos, samp, out);
  knn_kernel<<<dim3(MTOT), dim3(256), 0, stream>>>(pos, sqp, samp, h, out);
}